// Round 8
// baseline (651.581 us; speedup 1.0000x reference)
//
#include <hip/hip_runtime.h>
#include <stdint.h>

#define NROWS 8192
#define MROWS 65536
#define DDIM  512

// ---- 256x256 tile, BK=64 (2x K=32 halves), 8 waves, R4 schedule ----
// MFMA shape switched to 32x32x16 (2495 TF pipe vs 2075 for 16x16x32).
// Wave = 64 rows x 128 cols = 2x4 tiles of 32x32. Waves 4(wm) x 2(wn).
#define BM 256
#define BN 256
#define CT 8                       // col-tiles per block
#define KS_PER_CT 8                // 512 / 64
#define NT (CT * KS_PER_CT)        // 64 K-steps per block
#define GRID_X ((NROWS / BM) * (MROWS / (BN * CT)))  // 32 * 32 = 1024

typedef __attribute__((ext_vector_type(4)))  float f32x4;
typedef __attribute__((ext_vector_type(16))) float f32x16;
typedef __attribute__((ext_vector_type(8)))  short short8;
typedef unsigned short ushort_t;
typedef unsigned int   uint_t;

__device__ __forceinline__ ushort_t f2bf(float x) {
    uint_t u = __float_as_uint(x);
    u += 0x7fffu + ((u >> 16) & 1u);
    return (ushort_t)(u >> 16);
}
__device__ __forceinline__ float bf2f(ushort_t b) {
    return __uint_as_float(((uint_t)b) << 16);
}

__device__ __forceinline__ void gll16(const void* g, void* l) {
    __builtin_amdgcn_global_load_lds((__attribute__((address_space(1))) void*)g,
                                     (__attribute__((address_space(3))) void*)l,
                                     16, 0, 0);
}

#define SBAR()   __builtin_amdgcn_s_barrier()
#define SCHED0() __builtin_amdgcn_sched_barrier(0)
#define LGKM0()  asm volatile("s_waitcnt lgkmcnt(0)" ::: "memory")

// ---- init min buffer to +inf -------------------------------------------------
__global__ void init_minsq(uint_t* minsq) {
    int i = blockIdx.x * 256 + threadIdx.x;
    if (i < NROWS) minsq[i] = 0x7f800000u;  // +inf
}

// ---- fused fp32->bf16 convert (pre-swizzled) + row norms (verified R2-R7) ----
__global__ void convert_norms(const float* __restrict__ emb, const float* __restrict__ mem,
                              ushort_t* __restrict__ Abf, ushort_t* __restrict__ Bbf,
                              float* __restrict__ xsq, float* __restrict__ msq) {
    unsigned gid = blockIdx.x * 256 + threadIdx.x;
    unsigned row = gid >> 6;
    unsigned within = gid & 63u;
    unsigned seg = within >> 2, cc = within & 3u;
    int lane = threadIdx.x & 63;
    const float* src; ushort_t* dst; float* nrm; unsigned r;
    if (row < NROWS) { r = row;         src = emb + (size_t)r * DDIM; dst = Abf + (size_t)r * DDIM; nrm = xsq + r; }
    else             { r = row - NROWS; src = mem + (size_t)r * DDIM; dst = Bbf + (size_t)r * DDIM; nrm = msq + r; }
    unsigned scc = cc ^ ((r >> 1) & 3u);
    const float4* s4 = (const float4*)(src + seg * 32 + scc * 8);
    float4 a = s4[0], b = s4[1];
    ushort_t q[8];
    q[0]=f2bf(a.x); q[1]=f2bf(a.y); q[2]=f2bf(a.z); q[3]=f2bf(a.w);
    q[4]=f2bf(b.x); q[5]=f2bf(b.y); q[6]=f2bf(b.z); q[7]=f2bf(b.w);
    uint4 w;
    w.x = (uint_t)q[0] | ((uint_t)q[1] << 16);
    w.y = (uint_t)q[2] | ((uint_t)q[3] << 16);
    w.z = (uint_t)q[4] | ((uint_t)q[5] << 16);
    w.w = (uint_t)q[6] | ((uint_t)q[7] << 16);
    *(uint4*)(dst + seg * 32 + cc * 8) = w;
    float s = 0.f;
    #pragma unroll
    for (int i = 0; i < 8; ++i) { float v = bf2f(q[i]); s += v * v; }
    #pragma unroll
    for (int o = 1; o < 64; o <<= 1) s += __shfl_xor(s, o);
    if (lane == 0) *nrm = s;
}

// ---- main GEMM-min: R4 schedule, 32x32x16 MFMA ------------------------------
__global__ __launch_bounds__(512, 2) void gemm256_min(
    const ushort_t* __restrict__ Abf, const ushort_t* __restrict__ Bbf,
    const float* __restrict__ xsq, const float* __restrict__ msq,
    uint_t* __restrict__ minsq)
{
    // [dbuf][khalf][256 rows * 32 K] = 16 KiB each; A+B total 128 KiB
    __shared__ alignas(16) ushort_t As[2][2][256 * 32];
    __shared__ alignas(16) ushort_t Bs[2][2][256 * 32];
    __shared__ float Ms[BN * CT];   // 8 KiB msq panel

    const int tid  = threadIdx.x;
    const int lane = tid & 63;
    const int wave = tid >> 6;         // 0..7
    const int wm   = wave >> 1;        // 0..3  -> 64-row group
    const int wn   = wave & 1;         // 0..1  -> 128-col group
    const int col32  = lane & 31;      // A-row / B-col within a 32-tile
    const int khalf8 = lane >> 5;      // 0..1 -> k sub-chunk (8 bf16)

    // bijective XCD-chunked swizzle (1024 % 8 == 0)
    unsigned wg  = blockIdx.x;
    unsigned swz = (wg & 7u) * (GRID_X / 8) + (wg >> 3);
    const unsigned rt = swz & 31u;
    const unsigned cg = swz >> 5;
    const size_t r0    = (size_t)rt * BM;
    const size_t cbase = (size_t)cg * (BN * CT);

    // ds_read byte offsets within one [256][32] k-half buffer (row = 64 B).
    // For k16 sub-step h: logical chunk = 2h + khalf8, stored ^= (row>>1)&3.
    int offA32[2][2], offB32[4][2];
    #pragma unroll
    for (int m = 0; m < 2; ++m) {
        int r = wm * 64 + m * 32 + col32;
        #pragma unroll
        for (int h = 0; h < 2; ++h)
            offA32[m][h] = r * 64 + (((2 * h + khalf8) ^ ((r >> 1) & 3)) << 4);
    }
    #pragma unroll
    for (int n = 0; n < 4; ++n) {
        int r = wn * 128 + n * 32 + col32;
        #pragma unroll
        for (int h = 0; h < 2; ++h)
            offB32[n][h] = r * 64 + (((2 * h + khalf8) ^ ((r >> 1) & 3)) << 4);
    }

    // staging geometry: each gll16 statement covers rows {rowoff, rowoff+128}
    const int rowoff = wave * 16 + (lane >> 2);
    const int inrow  = (lane & 3) * 16;
    const char* Agb = (const char*)Abf + (r0 + rowoff) * 1024 + inrow;

    f32x16 acc[2][4];
    float runmin[2][16];
    #pragma unroll
    for (int m = 0; m < 2; ++m) {
        #pragma unroll
        for (int n = 0; n < 4; ++n) acc[m][n] = (f32x16)0.f;
        #pragma unroll
        for (int r = 0; r < 16; ++r) runmin[m][r] = 3.0e38f;
    }

    // ---- prologue ----
    // msq panel -> LDS; fence so the vmem queue is pure gll16 afterwards
    #pragma unroll
    for (int i = 0; i < 4; ++i) {
        int idx = i * 512 + tid;
        Ms[idx] = msq[cbase + idx];
    }
    asm volatile("s_waitcnt vmcnt(0)" ::: "memory");
    SCHED0();

    // stage K-step 0, issue order: B-k0, A-k0, B-k1, A-k1
    {
        const char* gB = (const char*)Bbf + (cbase + rowoff) * 1024 + inrow;
        char* lA = (char*)&As[0][0][0] + wave * 1024;
        char* lB = (char*)&Bs[0][0][0] + wave * 1024;
        gll16(gB,       lB);         gll16(gB + 131072,       lB + 8192);
        gll16(Agb,      lA);         gll16(Agb + 131072,      lA + 8192);
        gll16(gB + 64,  lB + 16384); gll16(gB + 64 + 131072,  lB + 16384 + 8192);
        gll16(Agb + 64, lA + 16384); gll16(Agb + 64 + 131072, lA + 16384 + 8192);
    }
    asm volatile("s_waitcnt vmcnt(4)" ::: "memory");   // B-k0, A-k0 landed
    SBAR();

    for (int t = 0; t < NT; ++t) {
        const int cur = t & 1, nxt = cur ^ 1;
        const bool stg = (t + 1) < NT;
        const int ks1 = (t + 1) & 7;
        const int ct1 = (t + 1) >> 3;
        const char* gA1 = Agb + (size_t)ks1 * 128;
        const char* gB1 = (const char*)Bbf + (cbase + (size_t)ct1 * BN + rowoff) * 1024 + inrow + (size_t)ks1 * 128;
        char* lA = (char*)&As[nxt][0][0] + wave * 1024;
        char* lB = (char*)&Bs[nxt][0][0] + wave * 1024;
        const char* rA = (const char*)&As[cur][0][0];
        const char* rB = (const char*)&Bs[cur][0][0];

        short8 af[2], bf[4];

        // ================= ph0: khalf 0, k16-sub 0 =================
        #pragma unroll
        for (int n = 0; n < 4; ++n) bf[n] = *(const short8*)(rB + offB32[n][0]);
        #pragma unroll
        for (int m = 0; m < 2; ++m) af[m] = *(const short8*)(rA + offA32[m][0]);
        if (stg) { gll16(gB1, lB); gll16(gB1 + 131072, lB + 8192); }
        SBAR();
        LGKM0(); SCHED0();
        __builtin_amdgcn_s_setprio(1);
        #pragma unroll
        for (int m = 0; m < 2; ++m)
            #pragma unroll
            for (int n = 0; n < 4; ++n)
                acc[m][n] = __builtin_amdgcn_mfma_f32_32x32x16_bf16(af[m], bf[n], acc[m][n], 0, 0, 0);
        __builtin_amdgcn_s_setprio(0);
        SBAR();

        // ================= ph1: khalf 0, k16-sub 1 =================
        #pragma unroll
        for (int n = 0; n < 4; ++n) bf[n] = *(const short8*)(rB + offB32[n][1]);
        #pragma unroll
        for (int m = 0; m < 2; ++m) af[m] = *(const short8*)(rA + offA32[m][1]);
        if (stg) { gll16(gA1, lA); gll16(gA1 + 131072, lA + 8192); }
        SBAR();
        LGKM0(); SCHED0();
        __builtin_amdgcn_s_setprio(1);
        #pragma unroll
        for (int m = 0; m < 2; ++m)
            #pragma unroll
            for (int n = 0; n < 4; ++n)
                acc[m][n] = __builtin_amdgcn_mfma_f32_32x32x16_bf16(af[m], bf[n], acc[m][n], 0, 0, 0);
        __builtin_amdgcn_s_setprio(0);
        if (stg) { asm volatile("s_waitcnt vmcnt(4)" ::: "memory"); }
        else     { asm volatile("s_waitcnt vmcnt(0)" ::: "memory"); }
        SBAR();   // publishes B-k1(t), A-k1(t)

        // ================= ph2: khalf 1, k16-sub 0 =================
        #pragma unroll
        for (int n = 0; n < 4; ++n) bf[n] = *(const short8*)(rB + 16384 + offB32[n][0]);
        #pragma unroll
        for (int m = 0; m < 2; ++m) af[m] = *(const short8*)(rA + 16384 + offA32[m][0]);
        if (stg) { gll16(gB1 + 64, lB + 16384); gll16(gB1 + 64 + 131072, lB + 16384 + 8192); }
        SBAR();
        LGKM0(); SCHED0();
        __builtin_amdgcn_s_setprio(1);
        #pragma unroll
        for (int m = 0; m < 2; ++m)
            #pragma unroll
            for (int n = 0; n < 4; ++n)
                acc[m][n] = __builtin_amdgcn_mfma_f32_32x32x16_bf16(af[m], bf[n], acc[m][n], 0, 0, 0);
        __builtin_amdgcn_s_setprio(0);
        SBAR();

        // ================= ph3: khalf 1, k16-sub 1 =================
        #pragma unroll
        for (int n = 0; n < 4; ++n) bf[n] = *(const short8*)(rB + 16384 + offB32[n][1]);
        #pragma unroll
        for (int m = 0; m < 2; ++m) af[m] = *(const short8*)(rA + 16384 + offA32[m][1]);
        if (stg) { gll16(gA1 + 64, lA + 16384); gll16(gA1 + 64 + 131072, lA + 16384 + 8192); }
        SBAR();
        LGKM0(); SCHED0();
        __builtin_amdgcn_s_setprio(1);
        #pragma unroll
        for (int m = 0; m < 2; ++m)
            #pragma unroll
            for (int n = 0; n < 4; ++n)
                acc[m][n] = __builtin_amdgcn_mfma_f32_32x32x16_bf16(af[m], bf[n], acc[m][n], 0, 0, 0);
        __builtin_amdgcn_s_setprio(0);
        if (stg) { asm volatile("s_waitcnt vmcnt(4)" ::: "memory"); }
        else     { asm volatile("s_waitcnt vmcnt(0)" ::: "memory"); }
        SBAR();   // publishes B-k0(t+1), A-k0(t+1)

        // ---- end of col-tile: fold acc into running min (msq from LDS) ----
        if ((t & 7) == 7) {
            const int ctf = t >> 3;
            float mc[4];
            #pragma unroll
            for (int n = 0; n < 4; ++n) mc[n] = Ms[ctf * 256 + wn * 128 + n * 32 + col32];
            #pragma unroll
            for (int m = 0; m < 2; ++m)
                #pragma unroll
                for (int n = 0; n < 4; ++n) {
                    #pragma unroll
                    for (int r = 0; r < 16; ++r)
                        runmin[m][r] = fminf(runmin[m][r], fmaf(-2.f, acc[m][n][r], mc[n]));
                    acc[m][n] = (f32x16)0.f;
                }
        }
    }

    // ---- epilogue: reduce over the 32 col-lanes, add row norm, atomicMin ----
    #pragma unroll
    for (int m = 0; m < 2; ++m)
        #pragma unroll
        for (int r = 0; r < 16; ++r) {
            float v = runmin[m][r];
            v = fminf(v, __shfl_xor(v, 1));
            v = fminf(v, __shfl_xor(v, 2));
            v = fminf(v, __shfl_xor(v, 4));
            v = fminf(v, __shfl_xor(v, 8));
            v = fminf(v, __shfl_xor(v, 16));
            if (col32 == 0) {
                int grow = (int)r0 + wm * 64 + m * 32 + (r & 3) + 8 * (r >> 2) + 4 * khalf8;
                float d2 = fmaxf(v + xsq[grow], 0.f);
                atomicMin(&minsq[grow], __float_as_uint(d2));
            }
        }
}

// ---- final sqrt --------------------------------------------------------------
__global__ void finish_kernel(const uint_t* __restrict__ minsq, float* __restrict__ out) {
    int i = blockIdx.x * 256 + threadIdx.x;
    if (i < NROWS) out[i] = sqrtf(__uint_as_float(minsq[i]));
}

// ======================= fallback path (ws too small) ========================
__global__ void norms_kernel(const float* __restrict__ emb, const float* __restrict__ mem,
                             float* __restrict__ xsq, float* __restrict__ msq) {
    int row  = blockIdx.x * 4 + (threadIdx.x >> 6);
    int lane = threadIdx.x & 63;
    const float* src; float* dst;
    if (row < NROWS) { src = emb + (size_t)row * DDIM;           dst = xsq + row; }
    else             { src = mem + (size_t)(row - NROWS) * DDIM; dst = msq + (row - NROWS); }
    float4 f0 = *(const float4*)(src + lane * 8);
    float4 f1 = *(const float4*)(src + lane * 8 + 4);
    float s = 0.f, v;
    v = bf2f(f2bf(f0.x)); s += v*v;  v = bf2f(f2bf(f0.y)); s += v*v;
    v = bf2f(f2bf(f0.z)); s += v*v;  v = bf2f(f2bf(f0.w)); s += v*v;
    v = bf2f(f2bf(f1.x)); s += v*v;  v = bf2f(f2bf(f1.y)); s += v*v;
    v = bf2f(f2bf(f1.z)); s += v*v;  v = bf2f(f2bf(f1.w)); s += v*v;
    #pragma unroll
    for (int o = 1; o < 64; o <<= 1) s += __shfl_xor(s, o);
    if (lane == 0) *dst = s;
}

__device__ __forceinline__ void fb_stage_load(const float* __restrict__ emb,
                                              const float* __restrict__ mem,
                                              size_t r0, size_t c0, int ks,
                                              float4* ra, float4* rb, int tid) {
    #pragma unroll
    for (int p = 0; p < 4; ++p) {
        int row = p * 32 + (tid >> 3);
        int c   = (tid & 7) * 8;
        const float* sa = emb + (r0 + row) * DDIM + ks * 64 + c;
        const float* sb = mem + (c0 + row) * DDIM + ks * 64 + c;
        ra[2*p]   = *(const float4*)sa;  ra[2*p+1] = *(const float4*)(sa + 4);
        rb[2*p]   = *(const float4*)sb;  rb[2*p+1] = *(const float4*)(sb + 4);
    }
}
__device__ __forceinline__ void fb_stage_write(ushort_t* Ab, ushort_t* Bb,
                                               const float4* ra, const float4* rb, int tid) {
    #pragma unroll
    for (int p = 0; p < 4; ++p) {
        int row = p * 32 + (tid >> 3);
        int ccs = (tid & 7) ^ (row & 7);
        uint4 wa, wb;
        wa.x = (uint_t)f2bf(ra[2*p].x)   | ((uint_t)f2bf(ra[2*p].y)   << 16);
        wa.y = (uint_t)f2bf(ra[2*p].z)   | ((uint_t)f2bf(ra[2*p].w)   << 16);
        wa.z = (uint_t)f2bf(ra[2*p+1].x) | ((uint_t)f2bf(ra[2*p+1].y) << 16);
        wa.w = (uint_t)f2bf(ra[2*p+1].z) | ((uint_t)f2bf(ra[2*p+1].w) << 16);
        wb.x = (uint_t)f2bf(rb[2*p].x)   | ((uint_t)f2bf(rb[2*p].y)   << 16);
        wb.y = (uint_t)f2bf(rb[2*p].z)   | ((uint_t)f2bf(rb[2*p].w)   << 16);
        wb.z = (uint_t)f2bf(rb[2*p+1].x) | ((uint_t)f2bf(rb[2*p+1].y) << 16);
        wb.w = (uint_t)f2bf(rb[2*p+1].z) | ((uint_t)f2bf(rb[2*p+1].w) << 16);
        *(uint4*)&Ab[row * 64 + ccs * 8] = wa;
        *(uint4*)&Bb[row * 64 + ccs * 8] = wb;
    }
}

__global__ __launch_bounds__(256, 2) void gemm_min_fb(
    const float* __restrict__ emb, const float* __restrict__ mem,
    const float* __restrict__ xsq, const float* __restrict__ msq,
    uint_t* __restrict__ minsq)
{
    __shared__ alignas(16) ushort_t Ab[128 * 64];
    __shared__ alignas(16) ushort_t Bb[128 * 64];
    const int tid = threadIdx.x, lane = tid & 63, wave = tid >> 6;
    const int wm = wave >> 1, wn = wave & 1;
    unsigned wg = blockIdx.x;
    unsigned swz = (wg & 7u) * (2048 / 8) + (wg >> 3);
    const unsigned rt = swz & 63u, cgf = swz >> 6;
    const size_t r0 = (size_t)rt * 128;
    float runmin[4][4];
    #pragma unroll
    for (int m = 0; m < 4; ++m)
        #pragma unroll
        for (int j = 0; j < 4; ++j) runmin[m][j] = 3.0e38f;
    float4 ra[8], rb[8];
    for (int ctf = 0; ctf < 16; ++ctf) {
        const size_t c0 = ((size_t)cgf * 16 + ctf) * 128;
        f32x4 acc[4][4] = {};
        fb_stage_load(emb, mem, r0, c0, 0, ra, rb, tid);
        for (int ks = 0; ks < 8; ++ks) {
            __syncthreads();
            fb_stage_write(Ab, Bb, ra, rb, tid);
            if (ks + 1 < 8) fb_stage_load(emb, mem, r0, c0, ks + 1, ra, rb, tid);
            __syncthreads();
            #pragma unroll
            for (int kk = 0; kk < 2; ++kk) {
                short8 af[4], bfm[4];
                #pragma unroll
                for (int m = 0; m < 4; ++m) {
                    int r = wm * 64 + m * 16 + (lane & 15);
                    int c = ((kk * 4 + (lane >> 4)) ^ (r & 7)) * 8;
                    af[m] = *(const short8*)&Ab[r * 64 + c];
                }
                #pragma unroll
                for (int n = 0; n < 4; ++n) {
                    int r = wn * 64 + n * 16 + (lane & 15);
                    int c = ((kk * 4 + (lane >> 4)) ^ (r & 7)) * 8;
                    bfm[n] = *(const short8*)&Bb[r * 64 + c];
                }
                #pragma unroll
                for (int m = 0; m < 4; ++m)
                    #pragma unroll
                    for (int n = 0; n < 4; ++n)
                        acc[m][n] = __builtin_amdgcn_mfma_f32_16x16x32_bf16(af[m], bfm[n], acc[m][n], 0, 0, 0);
            }
        }
        float mcf[4];
        #pragma unroll
        for (int n = 0; n < 4; ++n) mcf[n] = msq[c0 + wn * 64 + n * 16 + (lane & 15)];
        #pragma unroll
        for (int m = 0; m < 4; ++m)
            #pragma unroll
            for (int n = 0; n < 4; ++n)
                #pragma unroll
                for (int j = 0; j < 4; ++j)
                    runmin[m][j] = fminf(runmin[m][j], fmaf(-2.f, acc[m][n][j], mcf[n]));
    }
    #pragma unroll
    for (int m = 0; m < 4; ++m)
        #pragma unroll
        for (int j = 0; j < 4; ++j) {
            float v = runmin[m][j];
            v = fminf(v, __shfl_xor(v, 1));
            v = fminf(v, __shfl_xor(v, 2));
            v = fminf(v, __shfl_xor(v, 4));
            v = fminf(v, __shfl_xor(v, 8));
            if ((lane & 15) == 0) {
                int grow = (int)r0 + wm * 64 + m * 16 + (lane >> 4) * 4 + j;
                float d2 = fmaxf(v + xsq[grow], 0.f);
                atomicMin(&minsq[grow], __float_as_uint(d2));
            }
        }
}

extern "C" void kernel_launch(void* const* d_in, const int* in_sizes, int n_in,
                              void* d_out, int out_size, void* d_ws, size_t ws_size,
                              hipStream_t stream) {
    const float* emb = (const float*)d_in[0];
    const float* mem = (const float*)d_in[1];
    float* out = (float*)d_out;

    char* ws = (char*)d_ws;
    float*  xsq   = (float*)ws;                          // 32 KiB
    float*  msq   = (float*)(ws + 32768);                // 256 KiB
    uint_t* minsq = (uint_t*)(ws + 32768 + 262144);      // 32 KiB
    ushort_t* Abf = (ushort_t*)(ws + 327680);            // 8 MiB
    ushort_t* Bbf = Abf + (size_t)NROWS * DDIM;          // 64 MiB
    const size_t NEED = 327680 + ((size_t)NROWS + MROWS) * DDIM * 2;

    init_minsq<<<(NROWS + 255) / 256, 256, 0, stream>>>(minsq);
    if (ws_size >= NEED) {
        convert_norms<<<((NROWS + MROWS) * 64) / 256, 256, 0, stream>>>(emb, mem, Abf, Bbf, xsq, msq);
        gemm256_min<<<GRID_X, 512, 0, stream>>>(Abf, Bbf, xsq, msq, minsq);
    } else {
        norms_kernel<<<(NROWS + MROWS) / 4, 256, 0, stream>>>(emb, mem, xsq, msq);
        gemm_min_fb<<<2048, 256, 0, stream>>>(emb, mem, xsq, msq, minsq);
    }
    finish_kernel<<<(NROWS + 255) / 256, 256, 0, stream>>>(minsq, out);
}

// Round 9
// 546.802 us; speedup vs baseline: 1.1916x; 1.1916x over previous
//
#include <hip/hip_runtime.h>
#include <stdint.h>

#define NROWS 8192
#define MROWS 65536
#define DDIM  512

// ---- 256x256 tile, BK=64 (2x K=32 halves), 8 waves, m201-style 4-phase/K-step ----
// R4 configuration: best measured (513 us gemm, MfmaUtil 49, 0 bank conflicts).
// R5-R8 deviations (deeper pipeline x2, asymmetric depth, 32x32 MFMA) all regressed.
#define BM 256
#define BN 256
#define CT 8                       // col-tiles per block
#define KS_PER_CT 8                // 512 / 64
#define NT (CT * KS_PER_CT)        // 64 K-steps per block
#define GRID_X ((NROWS / BM) * (MROWS / (BN * CT)))  // 32 * 32 = 1024

typedef __attribute__((ext_vector_type(4))) float f32x4;
typedef __attribute__((ext_vector_type(8))) short short8;
typedef unsigned short ushort_t;
typedef unsigned int   uint_t;

__device__ __forceinline__ ushort_t f2bf(float x) {
    uint_t u = __float_as_uint(x);
    u += 0x7fffu + ((u >> 16) & 1u);
    return (ushort_t)(u >> 16);
}
__device__ __forceinline__ float bf2f(ushort_t b) {
    return __uint_as_float(((uint_t)b) << 16);
}

__device__ __forceinline__ void gll16(const void* g, void* l) {
    __builtin_amdgcn_global_load_lds((__attribute__((address_space(1))) void*)g,
                                     (__attribute__((address_space(3))) void*)l,
                                     16, 0, 0);
}

#define SBAR()   __builtin_amdgcn_s_barrier()
#define SCHED0() __builtin_amdgcn_sched_barrier(0)
#define LGKM0()  asm volatile("s_waitcnt lgkmcnt(0)" ::: "memory")

// ---- init min buffer to +inf -------------------------------------------------
__global__ void init_minsq(uint_t* minsq) {
    int i = blockIdx.x * 256 + threadIdx.x;
    if (i < NROWS) minsq[i] = 0x7f800000u;  // +inf
}

// ---- fused fp32->bf16 convert (pre-swizzled) + row norms (verified R2-R8) ----
__global__ void convert_norms(const float* __restrict__ emb, const float* __restrict__ mem,
                              ushort_t* __restrict__ Abf, ushort_t* __restrict__ Bbf,
                              float* __restrict__ xsq, float* __restrict__ msq) {
    unsigned gid = blockIdx.x * 256 + threadIdx.x;
    unsigned row = gid >> 6;
    unsigned within = gid & 63u;
    unsigned seg = within >> 2, cc = within & 3u;
    int lane = threadIdx.x & 63;
    const float* src; ushort_t* dst; float* nrm; unsigned r;
    if (row < NROWS) { r = row;         src = emb + (size_t)r * DDIM; dst = Abf + (size_t)r * DDIM; nrm = xsq + r; }
    else             { r = row - NROWS; src = mem + (size_t)r * DDIM; dst = Bbf + (size_t)r * DDIM; nrm = msq + r; }
    unsigned scc = cc ^ ((r >> 1) & 3u);
    const float4* s4 = (const float4*)(src + seg * 32 + scc * 8);
    float4 a = s4[0], b = s4[1];
    ushort_t q[8];
    q[0]=f2bf(a.x); q[1]=f2bf(a.y); q[2]=f2bf(a.z); q[3]=f2bf(a.w);
    q[4]=f2bf(b.x); q[5]=f2bf(b.y); q[6]=f2bf(b.z); q[7]=f2bf(b.w);
    uint4 w;
    w.x = (uint_t)q[0] | ((uint_t)q[1] << 16);
    w.y = (uint_t)q[2] | ((uint_t)q[3] << 16);
    w.z = (uint_t)q[4] | ((uint_t)q[5] << 16);
    w.w = (uint_t)q[6] | ((uint_t)q[7] << 16);
    *(uint4*)(dst + seg * 32 + cc * 8) = w;
    float s = 0.f;
    #pragma unroll
    for (int i = 0; i < 8; ++i) { float v = bf2f(q[i]); s += v * v; }
    #pragma unroll
    for (int o = 1; o < 64; o <<= 1) s += __shfl_xor(s, o);
    if (lane == 0) *nrm = s;
}

// ---- main GEMM-min: reads-before-barrier, counted vmcnt(4), 2 bar/phase ------
__global__ __launch_bounds__(512, 2) void gemm256_min(
    const ushort_t* __restrict__ Abf, const ushort_t* __restrict__ Bbf,
    const float* __restrict__ xsq, const float* __restrict__ msq,
    uint_t* __restrict__ minsq)
{
    // [dbuf][khalf][256 rows * 32 bf16] = 16 KiB each; A+B total 128 KiB
    __shared__ alignas(16) ushort_t As[2][2][256 * 32];
    __shared__ alignas(16) ushort_t Bs[2][2][256 * 32];
    __shared__ float Ms[BN * CT];   // 8 KiB: msq panel for this block

    const int tid  = threadIdx.x;
    const int lane = tid & 63;
    const int wave = tid >> 6;         // 0..7
    const int wm   = wave >> 2;        // 0..1  -> 128-row half
    const int wn   = wave & 3;         // 0..3  -> 64-col quarter
    const int laneRow = lane & 15;
    const int laneK   = lane >> 4;     // 0..3

    // bijective XCD-chunked swizzle (1024 % 8 == 0)
    unsigned wg  = blockIdx.x;
    unsigned swz = (wg & 7u) * (GRID_X / 8) + (wg >> 3);
    const unsigned rt = swz & 31u;
    const unsigned cg = swz >> 5;
    const size_t r0    = (size_t)rt * BM;
    const size_t cbase = (size_t)cg * (BN * CT);

    // ds_read byte offsets within one [256][32] k-half buffer (row = 64 B)
    const int chunk = ((laneK ^ ((laneRow >> 1) & 3)) << 4);
    int offA[8], offB[4];
    #pragma unroll
    for (int m = 0; m < 8; ++m) offA[m] = (wm * 128 + m * 16 + laneRow) * 64 + chunk;
    #pragma unroll
    for (int n = 0; n < 4; ++n) offB[n] = (wn * 64 + n * 16 + laneRow) * 64 + chunk;

    // staging geometry: each stage covers rows {rowoff, rowoff+128}
    const int rowoff = wave * 16 + (lane >> 2);
    const int inrow  = (lane & 3) * 16;
    const char* Agb = (const char*)Abf + (r0 + rowoff) * 1024 + inrow;

    f32x4 acc[8][4];
    float runmin[8][4];
    #pragma unroll
    for (int m = 0; m < 8; ++m)
        #pragma unroll
        for (int n = 0; n < 4; ++n) { acc[m][n] = (f32x4)0.f; runmin[m][n] = 3.0e38f; }

    // ---- prologue ----
    // msq panel -> LDS (keeps the vmem queue pure gll16 inside the loop)
    #pragma unroll
    for (int i = 0; i < 4; ++i) {
        int idx = i * 512 + tid;
        Ms[idx] = msq[cbase + idx];
    }
    LGKM0();

    // stage K-step 0, issue order: B-k0, A-k0, B-k1, A-k1
    {
        const char* gB = (const char*)Bbf + (cbase + rowoff) * 1024 + inrow;
        char* lA = (char*)&As[0][0][0] + wave * 1024;
        char* lB = (char*)&Bs[0][0][0] + wave * 1024;
        gll16(gB,       lB);         gll16(gB + 131072,      lB + 8192);
        gll16(Agb,      lA);         gll16(Agb + 131072,     lA + 8192);
        gll16(gB + 64,  lB + 16384); gll16(gB + 64 + 131072, lB + 16384 + 8192);
        gll16(Agb + 64, lA + 16384); gll16(Agb + 64 + 131072, lA + 16384 + 8192);
    }
    asm volatile("s_waitcnt vmcnt(4)" ::: "memory");   // B-k0, A-k0 landed
    SBAR();

    for (int t = 0; t < NT; ++t) {
        const int cur = t & 1, nxt = cur ^ 1;
        const bool stg = (t + 1) < NT;
        const int ks1 = (t + 1) & 7;
        const int ct1 = (t + 1) >> 3;
        const char* gA1 = Agb + ks1 * 128;
        const char* gB1 = (const char*)Bbf + (cbase + (size_t)ct1 * BN + rowoff) * 1024 + inrow + ks1 * 128;
        char* lA = (char*)&As[nxt][0][0] + wave * 1024;
        char* lB = (char*)&Bs[nxt][0][0] + wave * 1024;
        const char* rA = (const char*)&As[cur][0][0];
        const char* rB = (const char*)&Bs[cur][0][0];

        short8 a0[4], a1[4], b[4];

        // ================= ph0: kk0, m0-3 =================
        #pragma unroll
        for (int n = 0; n < 4; ++n) b[n]  = *(const short8*)(rB + offB[n]);
        #pragma unroll
        for (int m = 0; m < 4; ++m) a0[m] = *(const short8*)(rA + offA[m]);
        if (stg) { gll16(gB1, lB); gll16(gB1 + 131072, lB + 8192); }
        SBAR();
        LGKM0(); SCHED0();
        __builtin_amdgcn_s_setprio(1);
        #pragma unroll
        for (int m = 0; m < 4; ++m)
            #pragma unroll
            for (int n = 0; n < 4; ++n)
                acc[m][n] = __builtin_amdgcn_mfma_f32_16x16x32_bf16(a0[m], b[n], acc[m][n], 0, 0, 0);
        __builtin_amdgcn_s_setprio(0);
        SBAR();

        // ================= ph1: kk0, m4-7 =================
        #pragma unroll
        for (int m = 0; m < 4; ++m) a1[m] = *(const short8*)(rA + offA[m + 4]);
        if (stg) { gll16(gA1, lA); gll16(gA1 + 131072, lA + 8192); }
        SBAR();
        LGKM0(); SCHED0();
        __builtin_amdgcn_s_setprio(1);
        #pragma unroll
        for (int m = 0; m < 4; ++m)
            #pragma unroll
            for (int n = 0; n < 4; ++n)
                acc[m + 4][n] = __builtin_amdgcn_mfma_f32_16x16x32_bf16(a1[m], b[n], acc[m + 4][n], 0, 0, 0);
        __builtin_amdgcn_s_setprio(0);
        if (stg) { asm volatile("s_waitcnt vmcnt(4)" ::: "memory"); }
        else     { asm volatile("s_waitcnt vmcnt(0)" ::: "memory"); }
        SBAR();   // publishes B-k1(t), A-k1(t)

        // ================= ph2: kk1, m0-3 =================
        #pragma unroll
        for (int n = 0; n < 4; ++n) b[n]  = *(const short8*)(rB + 16384 + offB[n]);
        #pragma unroll
        for (int m = 0; m < 4; ++m) a0[m] = *(const short8*)(rA + 16384 + offA[m]);
        if (stg) { gll16(gB1 + 64, lB + 16384); gll16(gB1 + 64 + 131072, lB + 16384 + 8192); }
        SBAR();
        LGKM0(); SCHED0();
        __builtin_amdgcn_s_setprio(1);
        #pragma unroll
        for (int m = 0; m < 4; ++m)
            #pragma unroll
            for (int n = 0; n < 4; ++n)
                acc[m][n] = __builtin_amdgcn_mfma_f32_16x16x32_bf16(a0[m], b[n], acc[m][n], 0, 0, 0);
        __builtin_amdgcn_s_setprio(0);
        SBAR();

        // ================= ph3: kk1, m4-7 =================
        #pragma unroll
        for (int m = 0; m < 4; ++m) a1[m] = *(const short8*)(rA + 16384 + offA[m + 4]);
        if (stg) { gll16(gA1 + 64, lA + 16384); gll16(gA1 + 64 + 131072, lA + 16384 + 8192); }
        SBAR();
        LGKM0(); SCHED0();
        __builtin_amdgcn_s_setprio(1);
        #pragma unroll
        for (int m = 0; m < 4; ++m)
            #pragma unroll
            for (int n = 0; n < 4; ++n)
                acc[m + 4][n] = __builtin_amdgcn_mfma_f32_16x16x32_bf16(a1[m], b[n], acc[m + 4][n], 0, 0, 0);
        __builtin_amdgcn_s_setprio(0);
        if (stg) { asm volatile("s_waitcnt vmcnt(4)" ::: "memory"); }
        else     { asm volatile("s_waitcnt vmcnt(0)" ::: "memory"); }
        SBAR();   // publishes B-k0(t+1), A-k0(t+1)

        // ---- end of col-tile: fold acc into running min (msq from LDS) ----
        if ((t & 7) == 7) {
            const int ctf = t >> 3;
            float mc[4];
            #pragma unroll
            for (int n = 0; n < 4; ++n) mc[n] = Ms[ctf * 256 + wn * 64 + n * 16 + laneRow];
            #pragma unroll
            for (int m = 0; m < 8; ++m)
                #pragma unroll
                for (int n = 0; n < 4; ++n) {
                    #pragma unroll
                    for (int j = 0; j < 4; ++j)
                        runmin[m][j] = fminf(runmin[m][j], fmaf(-2.f, acc[m][n][j], mc[n]));
                    acc[m][n] = (f32x4)0.f;
                }
        }
    }

    // ---- epilogue: reduce over 16 col-lanes, add row norm, atomicMin ----
    #pragma unroll
    for (int m = 0; m < 8; ++m)
        #pragma unroll
        for (int j = 0; j < 4; ++j) {
            float v = runmin[m][j];
            v = fminf(v, __shfl_xor(v, 1));
            v = fminf(v, __shfl_xor(v, 2));
            v = fminf(v, __shfl_xor(v, 4));
            v = fminf(v, __shfl_xor(v, 8));
            if ((lane & 15) == 0) {
                int grow = (int)r0 + wm * 128 + m * 16 + laneK * 4 + j;
                float d2 = fmaxf(v + xsq[grow], 0.f);
                atomicMin(&minsq[grow], __float_as_uint(d2));
            }
        }
}

// ---- final sqrt --------------------------------------------------------------
__global__ void finish_kernel(const uint_t* __restrict__ minsq, float* __restrict__ out) {
    int i = blockIdx.x * 256 + threadIdx.x;
    if (i < NROWS) out[i] = sqrtf(__uint_as_float(minsq[i]));
}

// ======================= fallback path (ws too small) ========================
__global__ void norms_kernel(const float* __restrict__ emb, const float* __restrict__ mem,
                             float* __restrict__ xsq, float* __restrict__ msq) {
    int row  = blockIdx.x * 4 + (threadIdx.x >> 6);
    int lane = threadIdx.x & 63;
    const float* src; float* dst;
    if (row < NROWS) { src = emb + (size_t)row * DDIM;           dst = xsq + row; }
    else             { src = mem + (size_t)(row - NROWS) * DDIM; dst = msq + (row - NROWS); }
    float4 f0 = *(const float4*)(src + lane * 8);
    float4 f1 = *(const float4*)(src + lane * 8 + 4);
    float s = 0.f, v;
    v = bf2f(f2bf(f0.x)); s += v*v;  v = bf2f(f2bf(f0.y)); s += v*v;
    v = bf2f(f2bf(f0.z)); s += v*v;  v = bf2f(f2bf(f0.w)); s += v*v;
    v = bf2f(f2bf(f1.x)); s += v*v;  v = bf2f(f2bf(f1.y)); s += v*v;
    v = bf2f(f2bf(f1.z)); s += v*v;  v = bf2f(f2bf(f1.w)); s += v*v;
    #pragma unroll
    for (int o = 1; o < 64; o <<= 1) s += __shfl_xor(s, o);
    if (lane == 0) *dst = s;
}

__device__ __forceinline__ void fb_stage_load(const float* __restrict__ emb,
                                              const float* __restrict__ mem,
                                              size_t r0, size_t c0, int ks,
                                              float4* ra, float4* rb, int tid) {
    #pragma unroll
    for (int p = 0; p < 4; ++p) {
        int row = p * 32 + (tid >> 3);
        int c   = (tid & 7) * 8;
        const float* sa = emb + (r0 + row) * DDIM + ks * 64 + c;
        const float* sb = mem + (c0 + row) * DDIM + ks * 64 + c;
        ra[2*p]   = *(const float4*)sa;  ra[2*p+1] = *(const float4*)(sa + 4);
        rb[2*p]   = *(const float4*)sb;  rb[2*p+1] = *(const float4*)(sb + 4);
    }
}
__device__ __forceinline__ void fb_stage_write(ushort_t* Ab, ushort_t* Bb,
                                               const float4* ra, const float4* rb, int tid) {
    #pragma unroll
    for (int p = 0; p < 4; ++p) {
        int row = p * 32 + (tid >> 3);
        int ccs = (tid & 7) ^ (row & 7);
        uint4 wa, wb;
        wa.x = (uint_t)f2bf(ra[2*p].x)   | ((uint_t)f2bf(ra[2*p].y)   << 16);
        wa.y = (uint_t)f2bf(ra[2*p].z)   | ((uint_t)f2bf(ra[2*p].w)   << 16);
        wa.z = (uint_t)f2bf(ra[2*p+1].x) | ((uint_t)f2bf(ra[2*p+1].y) << 16);
        wa.w = (uint_t)f2bf(ra[2*p+1].z) | ((uint_t)f2bf(ra[2*p+1].w) << 16);
        wb.x = (uint_t)f2bf(rb[2*p].x)   | ((uint_t)f2bf(rb[2*p].y)   << 16);
        wb.y = (uint_t)f2bf(rb[2*p].z)   | ((uint_t)f2bf(rb[2*p].w)   << 16);
        wb.z = (uint_t)f2bf(rb[2*p+1].x) | ((uint_t)f2bf(rb[2*p+1].y) << 16);
        wb.w = (uint_t)f2bf(rb[2*p+1].z) | ((uint_t)f2bf(rb[2*p+1].w) << 16);
        *(uint4*)&Ab[row * 64 + ccs * 8] = wa;
        *(uint4*)&Bb[row * 64 + ccs * 8] = wb;
    }
}

__global__ __launch_bounds__(256, 2) void gemm_min_fb(
    const float* __restrict__ emb, const float* __restrict__ mem,
    const float* __restrict__ xsq, const float* __restrict__ msq,
    uint_t* __restrict__ minsq)
{
    __shared__ alignas(16) ushort_t Ab[128 * 64];
    __shared__ alignas(16) ushort_t Bb[128 * 64];
    const int tid = threadIdx.x, lane = tid & 63, wave = tid >> 6;
    const int wm = wave >> 1, wn = wave & 1;
    unsigned wg = blockIdx.x;
    unsigned swz = (wg & 7u) * (2048 / 8) + (wg >> 3);
    const unsigned rt = swz & 63u, cgf = swz >> 6;
    const size_t r0 = (size_t)rt * 128;
    float runmin[4][4];
    #pragma unroll
    for (int m = 0; m < 4; ++m)
        #pragma unroll
        for (int j = 0; j < 4; ++j) runmin[m][j] = 3.0e38f;
    float4 ra[8], rb[8];
    for (int ctf = 0; ctf < 16; ++ctf) {
        const size_t c0 = ((size_t)cgf * 16 + ctf) * 128;
        f32x4 acc[4][4] = {};
        fb_stage_load(emb, mem, r0, c0, 0, ra, rb, tid);
        for (int ks = 0; ks < 8; ++ks) {
            __syncthreads();
            fb_stage_write(Ab, Bb, ra, rb, tid);
            if (ks + 1 < 8) fb_stage_load(emb, mem, r0, c0, ks + 1, ra, rb, tid);
            __syncthreads();
            #pragma unroll
            for (int kk = 0; kk < 2; ++kk) {
                short8 af[4], bfm[4];
                #pragma unroll
                for (int m = 0; m < 4; ++m) {
                    int r = wm * 64 + m * 16 + (lane & 15);
                    int c = ((kk * 4 + (lane >> 4)) ^ (r & 7)) * 8;
                    af[m] = *(const short8*)&Ab[r * 64 + c];
                }
                #pragma unroll
                for (int n = 0; n < 4; ++n) {
                    int r = wn * 64 + n * 16 + (lane & 15);
                    int c = ((kk * 4 + (lane >> 4)) ^ (r & 7)) * 8;
                    bfm[n] = *(const short8*)&Bb[r * 64 + c];
                }
                #pragma unroll
                for (int m = 0; m < 4; ++m)
                    #pragma unroll
                    for (int n = 0; n < 4; ++n)
                        acc[m][n] = __builtin_amdgcn_mfma_f32_16x16x32_bf16(af[m], bfm[n], acc[m][n], 0, 0, 0);
            }
        }
        float mcf[4];
        #pragma unroll
        for (int n = 0; n < 4; ++n) mcf[n] = msq[c0 + wn * 64 + n * 16 + (lane & 15)];
        #pragma unroll
        for (int m = 0; m < 4; ++m)
            #pragma unroll
            for (int n = 0; n < 4; ++n)
                #pragma unroll
                for (int j = 0; j < 4; ++j)
                    runmin[m][j] = fminf(runmin[m][j], fmaf(-2.f, acc[m][n][j], mcf[n]));
    }
    #pragma unroll
    for (int m = 0; m < 4; ++m)
        #pragma unroll
        for (int j = 0; j < 4; ++j) {
            float v = runmin[m][j];
            v = fminf(v, __shfl_xor(v, 1));
            v = fminf(v, __shfl_xor(v, 2));
            v = fminf(v, __shfl_xor(v, 4));
            v = fminf(v, __shfl_xor(v, 8));
            if ((lane & 15) == 0) {
                int grow = (int)r0 + wm * 64 + m * 16 + (lane >> 4) * 4 + j;
                float d2 = fmaxf(v + xsq[grow], 0.f);
                atomicMin(&minsq[grow], __float_as_uint(d2));
            }
        }
}

extern "C" void kernel_launch(void* const* d_in, const int* in_sizes, int n_in,
                              void* d_out, int out_size, void* d_ws, size_t ws_size,
                              hipStream_t stream) {
    const float* emb = (const float*)d_in[0];
    const float* mem = (const float*)d_in[1];
    float* out = (float*)d_out;

    char* ws = (char*)d_ws;
    float*  xsq   = (float*)ws;                          // 32 KiB
    float*  msq   = (float*)(ws + 32768);                // 256 KiB
    uint_t* minsq = (uint_t*)(ws + 32768 + 262144);      // 32 KiB
    ushort_t* Abf = (ushort_t*)(ws + 327680);            // 8 MiB
    ushort_t* Bbf = Abf + (size_t)NROWS * DDIM;          // 64 MiB
    const size_t NEED = 327680 + ((size_t)NROWS + MROWS) * DDIM * 2;

    init_minsq<<<(NROWS + 255) / 256, 256, 0, stream>>>(minsq);
    if (ws_size >= NEED) {
        convert_norms<<<((NROWS + MROWS) * 64) / 256, 256, 0, stream>>>(emb, mem, Abf, Bbf, xsq, msq);
        gemm256_min<<<GRID_X, 512, 0, stream>>>(Abf, Bbf, xsq, msq, minsq);
    } else {
        norms_kernel<<<(NROWS + MROWS) / 4, 256, 0, stream>>>(emb, mem, xsq, msq);
        gemm_min_fb<<<2048, 256, 0, stream>>>(emb, mem, xsq, msq, minsq);
    }
    finish_kernel<<<(NROWS + 255) / 256, 256, 0, stream>>>(minsq, out);
}